// Round 12
// baseline (19.778 us; speedup 1.0000x reference)
//
#include <hip/hip_runtime.h>
#include <cmath>

// Problem constants (fixed by the reference)
#define B_ 256
#define I_ 1024
#define O_ 1024

typedef __attribute__((ext_vector_type(8))) short short8;   // 8 bf16 = 4 VGPRs
typedef __attribute__((ext_vector_type(4))) float f32x4;

// float -> bf16 bits, round-to-nearest-even (inputs finite after clamp)
__device__ inline unsigned f2bf(float f) {
  union { float f; unsigned u; } c;
  c.f = f;
  unsigned u = c.u;
  return (u + 0x7FFFu + ((u >> 16) & 1u)) >> 16;
}

// fast log(tanh(100|x|)) = log((1-t)/(1+t)), t = e^{-200|x|}  (HW exp/log)
// x==0: log(0) = -inf -> clamped to -1e30; exp(sum)=0 downstream (delta=0). ✓
__device__ inline float fast_lt(float xv) {
  float z = 100.0f * fabsf(xv);
  float t = __expf(-2.0f * z);
  float lt = __logf((1.0f - t) / (1.0f + t));
  return fmaxf(lt, -1e30f);
}

// ---------------------------------------------------------------------------
// Prep (R10-verified): 256 blocks x 512 threads.
//   all threads: wb = bf16(fc * (vw>0)), 8 elems each (mask derived later
//                from wb != 0)
//   threads 0..127: xb = bf16(x), ltb = bf16(log(tanh(100|x|)))
// ---------------------------------------------------------------------------
__global__ __launch_bounds__(512) void prep2(
    const float* __restrict__ x, const float* __restrict__ vw,
    const float* __restrict__ fcw, unsigned short* __restrict__ xb,
    unsigned short* __restrict__ ltb, unsigned short* __restrict__ wb) {
  const int t = threadIdx.x;
  const int bid = blockIdx.x;
  {
    size_t idx = ((size_t)bid * 512 + t) * 8;
    float4 v0 = *reinterpret_cast<const float4*>(vw + idx);
    float4 v1 = *reinterpret_cast<const float4*>(vw + idx + 4);
    float4 f0 = *reinterpret_cast<const float4*>(fcw + idx);
    float4 f1 = *reinterpret_cast<const float4*>(fcw + idx + 4);
    float va[8] = {v0.x, v0.y, v0.z, v0.w, v1.x, v1.y, v1.z, v1.w};
    float fa[8] = {f0.x, f0.y, f0.z, f0.w, f1.x, f1.y, f1.z, f1.w};
    short8 wv;
#pragma unroll
    for (int j = 0; j < 8; ++j)
      wv[j] = (va[j] > 0.0f) ? (short)f2bf(fa[j]) : (short)0;
    *reinterpret_cast<short8*>(wb + idx) = wv;
  }
  if (t < 128) {
    size_t idx = ((size_t)bid * 128 + t) * 8;
    float4 x0 = *reinterpret_cast<const float4*>(x + idx);
    float4 x1 = *reinterpret_cast<const float4*>(x + idx + 4);
    float xa[8] = {x0.x, x0.y, x0.z, x0.w, x1.x, x1.y, x1.z, x1.w};
    short8 xv, lv;
#pragma unroll
    for (int j = 0; j < 8; ++j) {
      xv[j] = (short)f2bf(xa[j]);
      lv[j] = (short)f2bf(fast_lt(xa[j]));
    }
    *reinterpret_cast<short8*>(xb + idx) = xv;
    *reinterpret_cast<short8*>(ltb + idx) = lv;
  }
}

// ---------------------------------------------------------------------------
// Dual MFMA GEMM, NO-LDS direct-gather variant.
// Key fact: an MFMA fragment read is lanes 0..15 -> 16 rows at k-offset
// lk=(lane>>4)*8 -> in GLOBAL memory that's 16 rows x one fully-used 64B
// line each (lanes {i,i+16,i+32,i+48} cover k+0..31 of row i contiguously).
// The bf16 ws (3MB) is L2-resident, so fragments are gathered straight from
// L2: no staging stores, no LDS fragment reads, no K-loop barriers, no
// prefetch registers. Fully-unrolled 8-slot K-loop -> up to 32 independent
// dwordx4 loads in flight; MFMA chain overlaps.
// Decomposition (R11-verified): 512 threads = 4 K-groups x 2 waves; group kg
// covers K-quarter [kg*256,+256); wave computes 16(M)x32(N) of both GEMMs.
// Mask fragment derived in-register from wf (wb!=0 -> bf16 1.0).
// LDS only for the 24KB cross-group reduce + fused exp/relu epilogue.
// XCD remap: xcd = bid&7 owns 4 consecutive n-blocks x all m.
// ---------------------------------------------------------------------------
__global__ __launch_bounds__(512) void mfma_fused7(
    const unsigned short* __restrict__ xb, const unsigned short* __restrict__ ltb,
    const unsigned short* __restrict__ wb, float* __restrict__ out) {
  const int bid = blockIdx.x;
  const int cx = bid & 7;               // XCD (round-robin dispatch)
  const int wi = bid >> 3;              // 0..31 within XCD
  const int nblk = cx * 4 + (wi >> 3);  // 0..31
  const int mblk = wi & 7;              // 0..7
  const int on0 = nblk * 32;
  const int bm0 = mblk * 32;

  __shared__ float red[3 * 128 * 16];   // 24 KB, cross-group reduce only

  const int t = threadIdx.x;
  const int lane = t & 63;
  const int wid = t >> 6;            // 0..7
  const int kg = wid >> 1;           // K-group 0..3: K-quarter [kg*256,+256)
  const int w2 = wid & 1;            // wave within group: m-half
  const int lr = lane & 15;
  const int lk = (lane >> 4) * 8;

  const int arow = bm0 + w2 * 16 + lr;   // A-side row this lane supplies
  const int brow0 = on0 + lr;            // B-side rows (n and n+16)
  const int brow1 = on0 + 16 + lr;
  const int k0 = kg * 256 + lk;

  const unsigned short* __restrict__ xpa = xb + (size_t)arow * I_ + k0;
  const unsigned short* __restrict__ lpa = ltb + (size_t)arow * I_ + k0;
  const unsigned short* __restrict__ wp0 = wb + (size_t)brow0 * I_ + k0;
  const unsigned short* __restrict__ wp1 = wb + (size_t)brow1 * I_ + k0;

  f32x4 z = {0.f, 0.f, 0.f, 0.f};
  f32x4 accd0 = z, accd1 = z, accs0 = z, accs1 = z;

#pragma unroll
  for (int ks = 0; ks < 8; ++ks) {       // 8 x K=32 slots = K-quarter of 256
    const int kb = ks * 32;
    short8 af  = *reinterpret_cast<const short8*>(xpa + kb);
    short8 lf  = *reinterpret_cast<const short8*>(lpa + kb);
    short8 wf0 = *reinterpret_cast<const short8*>(wp0 + kb);
    short8 wf1 = *reinterpret_cast<const short8*>(wp1 + kb);
    short8 mf0, mf1;
#pragma unroll
    for (int j = 0; j < 8; ++j) {
      mf0[j] = wf0[j] ? (short)0x3F80 : (short)0;
      mf1[j] = wf1[j] ? (short)0x3F80 : (short)0;
    }
    accd0 = __builtin_amdgcn_mfma_f32_16x16x32_bf16(af, wf0, accd0, 0, 0, 0);
    accd1 = __builtin_amdgcn_mfma_f32_16x16x32_bf16(af, wf1, accd1, 0, 0, 0);
    accs0 = __builtin_amdgcn_mfma_f32_16x16x32_bf16(lf, mf0, accs0, 0, 0, 0);
    accs1 = __builtin_amdgcn_mfma_f32_16x16x32_bf16(lf, mf1, accs1, 0, 0, 0);
  }

  // Cross-group reduce: kg 1..3 write 16 floats/lane, kg 0 accumulates.
  __syncthreads();
  if (kg > 0) {
    float* p = red + (((kg - 1) * 128 + w2 * 64 + lane) << 4);
#pragma unroll
    for (int r = 0; r < 4; ++r) {
      p[r] = accd0[r];
      p[4 + r] = accd1[r];
      p[8 + r] = accs0[r];
      p[12 + r] = accs1[r];
    }
  }
  __syncthreads();
  if (kg == 0) {
#pragma unroll
    for (int g = 0; g < 3; ++g) {
      const float* p = red + ((g * 128 + w2 * 64 + lane) << 4);
#pragma unroll
      for (int r = 0; r < 4; ++r) {
        accd0[r] += p[r];
        accd1[r] += p[4 + r];
        accs0[r] += p[8 + r];
        accs1[r] += p[12 + r];
      }
    }
    // C/D layout: col = lane&15, row = (lane>>4)*4 + reg   [m89-verified]
    const int orow = bm0 + w2 * 16 + (lane >> 4) * 4;
    const int ocol = on0 + lr;
#pragma unroll
    for (int r = 0; r < 4; ++r) {
      float d0 = __expf(accs0[r]);
      float d1 = __expf(accs1[r]);
      float y0 = fmaxf(accd0[r] * d0, 0.0f);
      float y1 = fmaxf(accd1[r] * d1, 0.0f);
      size_t off0 = (size_t)(orow + r) * O_ + ocol;
      out[off0] = y0;
      out[off0 + 16] = y1;
      out[(size_t)B_ * O_ + off0] = d0;
      out[(size_t)B_ * O_ + off0 + 16] = d1;
    }
  }
}

// ---------------------------------------------------------------------------
// fp32 fallback (workspace too small): inline log-tanh, fused epilogue
// ---------------------------------------------------------------------------
__global__ __launch_bounds__(256) void dual_gemm_f32(
    const float* __restrict__ x, const float* __restrict__ vw,
    const float* __restrict__ fcw, float* __restrict__ out) {
  const int on0 = blockIdx.x * 64;
  const int bm0 = blockIdx.y * 64;
  __shared__ float xs[32][68];
  __shared__ float ls[32][68];
  __shared__ float wsm[32][68];
  __shared__ float msh[32][68];
  const int t = threadIdx.x;
  const int tx = t & 15, ty = t >> 4;
  const int m0 = ty * 4, n0 = tx * 4;
  float accd[4][4] = {{0.f}};
  float accs[4][4] = {{0.f}};
  for (int kt = 0; kt < I_; kt += 32) {
#pragma unroll
    for (int j = 0; j < 8; ++j) {
      int f = j * 256 + t;
      int m = f >> 5;
      int kk = f & 31;
      int gk = kt + kk;
      float xv = x[(size_t)(bm0 + m) * I_ + gk];
      xs[kk][m] = xv;
      ls[kk][m] = fast_lt(xv);
      float vv = vw[(size_t)(on0 + m) * I_ + gk];
      float fv = fcw[(size_t)(on0 + m) * I_ + gk];
      float mk = vv > 0.0f ? 1.0f : 0.0f;
      wsm[kk][m] = fv * mk;
      msh[kk][m] = mk;
    }
    __syncthreads();
#pragma unroll
    for (int kk = 0; kk < 32; ++kk) {
      float4 xv = *reinterpret_cast<const float4*>(&xs[kk][m0]);
      float4 lv = *reinterpret_cast<const float4*>(&ls[kk][m0]);
      float4 wv = *reinterpret_cast<const float4*>(&wsm[kk][n0]);
      float4 mv = *reinterpret_cast<const float4*>(&msh[kk][n0]);
      float xa[4] = {xv.x, xv.y, xv.z, xv.w};
      float la[4] = {lv.x, lv.y, lv.z, lv.w};
      float wa[4] = {wv.x, wv.y, wv.z, wv.w};
      float ma[4] = {mv.x, mv.y, mv.z, mv.w};
#pragma unroll
      for (int i = 0; i < 4; ++i)
#pragma unroll
        for (int jj = 0; jj < 4; ++jj) {
          accd[i][jj] = fmaf(xa[i], wa[jj], accd[i][jj]);
          accs[i][jj] = fmaf(la[i], ma[jj], accs[i][jj]);
        }
    }
    __syncthreads();
  }
#pragma unroll
  for (int i = 0; i < 4; ++i) {
    int row = bm0 + m0 + i;
#pragma unroll
    for (int jj = 0; jj < 4; ++jj) {
      float delta = __expf(accs[i][jj]);
      out[(size_t)row * O_ + on0 + n0 + jj] = fmaxf(accd[i][jj] * delta, 0.0f);
      out[(size_t)B_ * O_ + (size_t)row * O_ + on0 + n0 + jj] = delta;
    }
  }
}

extern "C" void kernel_launch(void* const* d_in, const int* in_sizes, int n_in,
                              void* d_out, int out_size, void* d_ws,
                              size_t ws_size, hipStream_t stream) {
  const float* x = (const float*)d_in[0];
  const float* vw = (const float*)d_in[1];
  const float* fcw = (const float*)d_in[2];
  float* out = (float*)d_out;

  const size_t xbB = (size_t)B_ * I_ * 2;  // 512 KB
  const size_t wbB = (size_t)O_ * I_ * 2;  // 2 MB
  const size_t needB = 2 * xbB + wbB;      // 3 MB total

  unsigned short* xb = (unsigned short*)d_ws;
  unsigned short* ltb = (unsigned short*)((char*)d_ws + xbB);
  unsigned short* wb = (unsigned short*)((char*)d_ws + 2 * xbB);

  if (ws_size >= needB) {
    prep2<<<256, 512, 0, stream>>>(x, vw, fcw, xb, ltb, wb);
    mfma_fused7<<<256, 512, 0, stream>>>(xb, ltb, wb, out);
  } else {
    dual_gemm_f32<<<dim3(O_ / 64, B_ / 64, 1), 256, 0, stream>>>(x, vw, fcw, out);
  }
}

// Round 13
// 16.314 us; speedup vs baseline: 1.2124x; 1.2124x over previous
//
#include <hip/hip_runtime.h>
#include <cmath>

// Problem constants (fixed by the reference)
#define B_ 256
#define I_ 1024
#define O_ 1024

typedef __attribute__((ext_vector_type(8))) short short8;   // 8 bf16 = 4 VGPRs
typedef __attribute__((ext_vector_type(4))) float f32x4;

// float -> bf16 bits, round-to-nearest-even (inputs finite after clamp)
__device__ inline unsigned f2bf(float f) {
  union { float f; unsigned u; } c;
  c.f = f;
  unsigned u = c.u;
  return (u + 0x7FFFu + ((u >> 16) & 1u)) >> 16;
}

// fast log(tanh(100|x|)) = log((1-t)/(1+t)), t = e^{-200|x|}  (HW exp/log)
// x==0: log(0) = -inf -> clamped to -1e30; exp(sum)=0 downstream (delta=0). ✓
__device__ inline float fast_lt(float xv) {
  float z = 100.0f * fabsf(xv);
  float t = __expf(-2.0f * z);
  float lt = __logf((1.0f - t) / (1.0f + t));
  return fmaxf(lt, -1e30f);
}

// ---------------------------------------------------------------------------
// Prep (R10-verified, unchanged): 256 blocks x 512 threads.
//   all threads: wb = bf16(fc * (vw>0)), 8 elems each (mask derived later
//                from wb != 0)
//   threads 0..127: xb = bf16(x), ltb = bf16(log(tanh(100|x|)))
// ---------------------------------------------------------------------------
__global__ __launch_bounds__(512) void prep2(
    const float* __restrict__ x, const float* __restrict__ vw,
    const float* __restrict__ fcw, unsigned short* __restrict__ xb,
    unsigned short* __restrict__ ltb, unsigned short* __restrict__ wb) {
  const int t = threadIdx.x;
  const int bid = blockIdx.x;
  {
    size_t idx = ((size_t)bid * 512 + t) * 8;
    float4 v0 = *reinterpret_cast<const float4*>(vw + idx);
    float4 v1 = *reinterpret_cast<const float4*>(vw + idx + 4);
    float4 f0 = *reinterpret_cast<const float4*>(fcw + idx);
    float4 f1 = *reinterpret_cast<const float4*>(fcw + idx + 4);
    float va[8] = {v0.x, v0.y, v0.z, v0.w, v1.x, v1.y, v1.z, v1.w};
    float fa[8] = {f0.x, f0.y, f0.z, f0.w, f1.x, f1.y, f1.z, f1.w};
    short8 wv;
#pragma unroll
    for (int j = 0; j < 8; ++j)
      wv[j] = (va[j] > 0.0f) ? (short)f2bf(fa[j]) : (short)0;
    *reinterpret_cast<short8*>(wb + idx) = wv;
  }
  if (t < 128) {
    size_t idx = ((size_t)bid * 128 + t) * 8;
    float4 x0 = *reinterpret_cast<const float4*>(x + idx);
    float4 x1 = *reinterpret_cast<const float4*>(x + idx + 4);
    float xa[8] = {x0.x, x0.y, x0.z, x0.w, x1.x, x1.y, x1.z, x1.w};
    short8 xv, lv;
#pragma unroll
    for (int j = 0; j < 8; ++j) {
      xv[j] = (short)f2bf(xa[j]);
      lv[j] = (short)f2bf(fast_lt(xa[j]));
    }
    *reinterpret_cast<short8*>(xb + idx) = xv;
    *reinterpret_cast<short8*>(ltb + idx) = lv;
  }
}

// ---------------------------------------------------------------------------
// Dual MFMA GEMM, 2-blocks/CU variant (R11 pipeline, halved M-tile).
// Tile 16(M) x 32(N); grid = 32n x 16m = 512 blocks -> 2 blocks/CU,
// 4 waves/SIMD (vs R11's 2): doubles TLP to hide stage/barrier/LDS latency.
// 512 threads = 4 K-groups (kg = wid>>1) x 2 waves; kg covers K-quarter
// [kg*256,+256) in 4 iters of BK=64. Wave computes 16x16 of BOTH GEMMs
// (cols on0 + w2*16): per ks reads {af, lf, wf} = 3 frags for 2 MFMAs; mask
// derived in-register from wf (wb!=0 -> bf16 1.0).
// Chip-wide LDS traffic identical to R11 (per-block halves, blocks double).
// LDS per kg: rows 0-15 A, 16-31 L, 32-63 W; 72-short rows (144B = 9x16B,
// conflict-free for b128 stores+reads, R4-verified skew).
// Cross-group: 12KB LDS reduce + fused exp/relu epilogue.
// __launch_bounds__(512,4): 4 waves/EU min -> guarantees 2-block co-residency.
// XCD remap: cx = bid&7 owns 4 n-blocks x all 16 m-blocks (~1.5MB/XCD in L2).
// ---------------------------------------------------------------------------
__global__ __launch_bounds__(512, 4) void mfma_fused8(
    const unsigned short* __restrict__ xb, const unsigned short* __restrict__ ltb,
    const unsigned short* __restrict__ wb, float* __restrict__ out) {
  const int bid = blockIdx.x;
  const int cx = bid & 7;               // XCD (round-robin dispatch)
  const int wi = bid >> 3;              // 0..63 within XCD
  const int nblk = cx * 4 + (wi >> 4);  // 0..31
  const int mblk = wi & 15;             // 0..15
  const int on0 = nblk * 32;
  const int bm0 = mblk * 16;

  __shared__ short lds[4][64][72];      // [kg][row: 0-15 A, 16-31 L, 32-63 W]

  const int t = threadIdx.x;
  const int lane = t & 63;
  const int wid = t >> 6;            // 0..7
  const int kg = wid >> 1;           // K-group 0..3: K-quarter [kg*256,+256)
  const int w2 = wid & 1;            // wave within group: n-half
  const int lr = lane & 15;
  const int lk = (lane >> 4) * 8;

  const int tl = t & 127;            // thread index within group
  const int ar = tl >> 3;            // A/L staging row 0..15
  const int ac = (tl & 7) * 8;       // A/L staging col (elems)
  const int wr = tl >> 2;            // W staging row 0..31
  const int wc = (tl & 3) * 16;      // W staging col (elems)

  const size_t aoff = (size_t)(bm0 + ar) * I_ + kg * 256 + ac;
  const size_t boff = (size_t)(on0 + wr) * I_ + kg * 256 + wc;

  // prefetch tile 0 of this group's K-quarter
  short8 ra = *reinterpret_cast<const short8*>(xb + aoff);
  short8 rlv = *reinterpret_cast<const short8*>(ltb + aoff);
  short8 rw0 = *reinterpret_cast<const short8*>(wb + boff);
  short8 rw1 = *reinterpret_cast<const short8*>(wb + boff + 8);

  f32x4 accd = {0.f, 0.f, 0.f, 0.f};
  f32x4 accs = {0.f, 0.f, 0.f, 0.f};

  for (int kt = 0; kt < 256; kt += 64) {
    __syncthreads();  // previous iter's LDS reads done before overwrite
    *reinterpret_cast<short8*>(&lds[kg][ar][ac]) = ra;
    *reinterpret_cast<short8*>(&lds[kg][16 + ar][ac]) = rlv;
    *reinterpret_cast<short8*>(&lds[kg][32 + wr][wc]) = rw0;
    *reinterpret_cast<short8*>(&lds[kg][32 + wr][wc + 8]) = rw1;
    if (kt + 64 < 256) {  // issue next-tile loads; latency hides under MFMA
      ra = *reinterpret_cast<const short8*>(xb + aoff + kt + 64);
      rlv = *reinterpret_cast<const short8*>(ltb + aoff + kt + 64);
      rw0 = *reinterpret_cast<const short8*>(wb + boff + kt + 64);
      rw1 = *reinterpret_cast<const short8*>(wb + boff + kt + 72);
    }
    __syncthreads();
#pragma unroll
    for (int ks = 0; ks < 2; ++ks) {
      const int kb = ks * 32 + lk;
      short8 af = *reinterpret_cast<const short8*>(&lds[kg][lr][kb]);
      short8 lf = *reinterpret_cast<const short8*>(&lds[kg][16 + lr][kb]);
      short8 wf = *reinterpret_cast<const short8*>(&lds[kg][32 + w2 * 16 + lr][kb]);
      short8 mf;
#pragma unroll
      for (int j = 0; j < 8; ++j)
        mf[j] = wf[j] ? (short)0x3F80 : (short)0;
      accd = __builtin_amdgcn_mfma_f32_16x16x32_bf16(af, wf, accd, 0, 0, 0);
      accs = __builtin_amdgcn_mfma_f32_16x16x32_bf16(lf, mf, accs, 0, 0, 0);
    }
  }

  // Cross-group reduce: kg 1..3 write 8 floats/lane, kg 0 accumulates.
  __syncthreads();
  float* red = reinterpret_cast<float*>(&lds[0][0][0]);  // 12KB < 36KB
  if (kg > 0) {
    float* p = red + (((kg - 1) * 128 + w2 * 64 + lane) << 3);
#pragma unroll
    for (int r = 0; r < 4; ++r) {
      p[r] = accd[r];
      p[4 + r] = accs[r];
    }
  }
  __syncthreads();
  if (kg == 0) {
#pragma unroll
    for (int g = 0; g < 3; ++g) {
      const float* p = red + ((g * 128 + w2 * 64 + lane) << 3);
#pragma unroll
      for (int r = 0; r < 4; ++r) {
        accd[r] += p[r];
        accs[r] += p[4 + r];
      }
    }
    // C/D layout: col = lane&15, row = (lane>>4)*4 + reg   [m89-verified]
    const int orow = bm0 + (lane >> 4) * 4;
    const int ocol = on0 + w2 * 16 + lr;
#pragma unroll
    for (int r = 0; r < 4; ++r) {
      float d = __expf(accs[r]);
      float y = fmaxf(accd[r] * d, 0.0f);
      size_t off = (size_t)(orow + r) * O_ + ocol;
      out[off] = y;
      out[(size_t)B_ * O_ + off] = d;
    }
  }
}

// ---------------------------------------------------------------------------
// fp32 fallback (workspace too small): inline log-tanh, fused epilogue
// ---------------------------------------------------------------------------
__global__ __launch_bounds__(256) void dual_gemm_f32(
    const float* __restrict__ x, const float* __restrict__ vw,
    const float* __restrict__ fcw, float* __restrict__ out) {
  const int on0 = blockIdx.x * 64;
  const int bm0 = blockIdx.y * 64;
  __shared__ float xs[32][68];
  __shared__ float ls[32][68];
  __shared__ float wsm[32][68];
  __shared__ float msh[32][68];
  const int t = threadIdx.x;
  const int tx = t & 15, ty = t >> 4;
  const int m0 = ty * 4, n0 = tx * 4;
  float accd[4][4] = {{0.f}};
  float accs[4][4] = {{0.f}};
  for (int kt = 0; kt < I_; kt += 32) {
#pragma unroll
    for (int j = 0; j < 8; ++j) {
      int f = j * 256 + t;
      int m = f >> 5;
      int kk = f & 31;
      int gk = kt + kk;
      float xv = x[(size_t)(bm0 + m) * I_ + gk];
      xs[kk][m] = xv;
      ls[kk][m] = fast_lt(xv);
      float vv = vw[(size_t)(on0 + m) * I_ + gk];
      float fv = fcw[(size_t)(on0 + m) * I_ + gk];
      float mk = vv > 0.0f ? 1.0f : 0.0f;
      wsm[kk][m] = fv * mk;
      msh[kk][m] = mk;
    }
    __syncthreads();
#pragma unroll
    for (int kk = 0; kk < 32; ++kk) {
      float4 xv = *reinterpret_cast<const float4*>(&xs[kk][m0]);
      float4 lv = *reinterpret_cast<const float4*>(&ls[kk][m0]);
      float4 wv = *reinterpret_cast<const float4*>(&wsm[kk][n0]);
      float4 mv = *reinterpret_cast<const float4*>(&msh[kk][n0]);
      float xa[4] = {xv.x, xv.y, xv.z, xv.w};
      float la[4] = {lv.x, lv.y, lv.z, lv.w};
      float wa[4] = {wv.x, wv.y, wv.z, wv.w};
      float ma[4] = {mv.x, mv.y, mv.z, mv.w};
#pragma unroll
      for (int i = 0; i < 4; ++i)
#pragma unroll
        for (int jj = 0; jj < 4; ++jj) {
          accd[i][jj] = fmaf(xa[i], wa[jj], accd[i][jj]);
          accs[i][jj] = fmaf(la[i], ma[jj], accs[i][jj]);
        }
    }
    __syncthreads();
  }
#pragma unroll
  for (int i = 0; i < 4; ++i) {
    int row = bm0 + m0 + i;
#pragma unroll
    for (int jj = 0; jj < 4; ++jj) {
      float delta = __expf(accs[i][jj]);
      out[(size_t)row * O_ + on0 + n0 + jj] = fmaxf(accd[i][jj] * delta, 0.0f);
      out[(size_t)B_ * O_ + (size_t)row * O_ + on0 + n0 + jj] = delta;
    }
  }
}

extern "C" void kernel_launch(void* const* d_in, const int* in_sizes, int n_in,
                              void* d_out, int out_size, void* d_ws,
                              size_t ws_size, hipStream_t stream) {
  const float* x = (const float*)d_in[0];
  const float* vw = (const float*)d_in[1];
  const float* fcw = (const float*)d_in[2];
  float* out = (float*)d_out;

  const size_t xbB = (size_t)B_ * I_ * 2;  // 512 KB
  const size_t wbB = (size_t)O_ * I_ * 2;  // 2 MB
  const size_t needB = 2 * xbB + wbB;      // 3 MB total

  unsigned short* xb = (unsigned short*)d_ws;
  unsigned short* ltb = (unsigned short*)((char*)d_ws + xbB);
  unsigned short* wb = (unsigned short*)((char*)d_ws + 2 * xbB);

  if (ws_size >= needB) {
    prep2<<<256, 512, 0, stream>>>(x, vw, fcw, xb, ltb, wb);
    mfma_fused8<<<512, 512, 0, stream>>>(xb, ltb, wb, out);
  } else {
    dual_gemm_f32<<<dim3(O_ / 64, B_ / 64, 1), 256, 0, stream>>>(x, vw, fcw, out);
  }
}